// Round 8
// baseline (918.175 us; speedup 1.0000x reference)
//
#include <hip/hip_runtime.h>
#include <cstdint>
#include <cstddef>

typedef _Float16 h8 __attribute__((ext_vector_type(8)));
typedef float f4 __attribute__((ext_vector_type(4)));
typedef float f16f __attribute__((ext_vector_type(16)));

#define DEV static __device__ __forceinline__

DEV void gld16(const void* g, void* l) {
  __builtin_amdgcn_global_load_lds(
      (const __attribute__((address_space(1))) void*)g,
      (__attribute__((address_space(3))) void*)l, 16, 0, 0);
}

// RBF expansion: basis_g = exp(-((h-gv_g)*1.75)^2), gv_g = -2 + (4/7)g
// (h-gv)*1.75 = 1.75h + 3.5 - g  -> one fma, then 8x (sub,mul,exp)
DEV h8 rbf8(float h) {
  const float a = fmaf(h, 1.75f, 3.5f);
  union { h8 v; _Float16 u[8]; } o;
#pragma unroll
  for (int g = 0; g < 8; ++g) {
    const float d = a - (float)g;
    o.u[g] = (_Float16)__expf(-d * d);
  }
  return o.v;
}

// ---------- kan_prep2: 32 rows/block. LayerNorm stats, then:
//  Ht[c][m]  (fp16, transposed [768][8192])   — GEMM h-loads coalesce on m
//  Sf fragment-order silu: chunk (m,cc) at (mb*12 + cc>>3)*2048 +
//      (((cc>>1)&3)*64 + (m&31) + 32*(cc&1))*8   — 512B-contiguous runs
__global__ __launch_bounds__(256)
void kan_prep2(const float* __restrict__ X, const float* __restrict__ lnw,
               const float* __restrict__ lnb, _Float16* __restrict__ Ht,
               _Float16* __restrict__ Sf) {
  const int mb = blockIdx.x;
  const int R = mb * 32;
  const int t = threadIdx.x;
  __shared__ float mu_[32], rs_[32];
  {  // stats: 8 threads per row
    const int r = t >> 3, p = t & 7;
    const float* xr = X + (size_t)(R + r) * 768;
    float s = 0.f, q = 0.f;
    for (int i = 0; i < 96; ++i) {
      const float v = xr[p + 8 * i];
      s += v; q += v * v;
    }
    s += __shfl_xor(s, 1); q += __shfl_xor(q, 1);
    s += __shfl_xor(s, 2); q += __shfl_xor(q, 2);
    s += __shfl_xor(s, 4); q += __shfl_xor(q, 4);
    if (p == 0) {
      const float mu = s * (1.f / 768.f);
      mu_[r] = mu;
      rs_[r] = rsqrtf(q * (1.f / 768.f) - mu * mu + 1e-5f);
    }
  }
  __syncthreads();
  const int r = t & 31, cb = t >> 5;
  const float mu = mu_[r], rsg = rs_[r];
  // Ht: consecutive lanes (=consecutive m) write 64B runs
  for (int i = 0; i < 96; ++i) {
    const int c = cb + 8 * i;
    const float x = X[(size_t)(R + r) * 768 + c];
    const float h = (x - mu) * rsg * lnw[c] + lnb[c];
    Ht[(size_t)c * 8192 + R + r] = (_Float16)h;
  }
  // Sf: per-thread 8-consecutive-c silu chunk, 512B-contiguous across lanes
  for (int j = 0; j < 12; ++j) {
    const int cc = cb + 8 * j;
    const float* xp = X + (size_t)(R + r) * 768 + cc * 8;
    union { h8 v; _Float16 u[8]; } sv;
#pragma unroll
    for (int g = 0; g < 8; ++g) {
      const float x = xp[g];
      sv.u[g] = (_Float16)(x / (1.f + __expf(-x)));
    }
    const size_t addr = ((size_t)mb * 12 + (cc >> 3)) * 2048 +
                        (size_t)(((cc >> 1) & 3) * 64 + r + 32 * (cc & 1)) * 8;
    *(h8*)(Sf + addr) = sv.v;
  }
}

// ---------- weight cast + FRAGMENT-SWIZZLE (r6-proven): W fp32 [K][N] -> Bp
// frag (n, k..k+7) at ((n>>5)*nkt + (k>>6))*2048 +
//   (((k>>4)&3)*64 + (n&31) + 32*((k>>3)&1))*8
__global__ __launch_bounds__(256)
void wt_cast(const float* __restrict__ W, _Float16* __restrict__ Bp,
             int N, int koff, int nkt) {
  __shared__ float t[32][33];
  const int k0 = blockIdx.x * 32, n0 = blockIdx.y * 32;
  const int tx = threadIdx.x & 31, ty = threadIdx.x >> 5;
#pragma unroll
  for (int i = 0; i < 4; ++i)
    t[ty + i * 8][tx] = W[(size_t)(k0 + ty + i * 8) * N + n0 + tx];
  __syncthreads();
  const int f = threadIdx.x;
  if (f < 128) {
    const int nn = f & 31, cc = f >> 5;
    union { h8 v; _Float16 u[8]; } bs;
#pragma unroll
    for (int j = 0; j < 8; ++j) bs.u[j] = (_Float16)t[cc * 8 + j][nn];
    const int kg = koff + k0 + cc * 8;
    const int nt = (n0 + nn) >> 5;
    const size_t addr = ((size_t)nt * nkt + (kg >> 6)) * 2048 +
                        (size_t)((((kg >> 4) & 3) * 64 + nn + 32 * ((kg >> 3) & 1))) * 8;
    *(h8*)(Bp + addr) = bs.v;
  }
}

// ---------- V transpose: qkv fp16 [8192][2304] -> Vt [96*64][1024]
__global__ __launch_bounds__(256)
void v_transpose(const _Float16* __restrict__ qkv, _Float16* __restrict__ Vt) {
  const int bh = blockIdx.z, hh = bh % 12, b = bh / 12;
  const int kvb = blockIdx.x * 32, db = blockIdx.y * 32;
  __shared__ _Float16 t[32][33];
  const int tx = threadIdx.x & 31, ty = threadIdx.x >> 5;
#pragma unroll
  for (int i = 0; i < 4; ++i) {
    const int kv = kvb + ty + i * 8;
    t[ty + i * 8][tx] = qkv[(size_t)(b * 1024 + kv) * 2304 + 1536 + hh * 64 + db + tx];
  }
  __syncthreads();
#pragma unroll
  for (int i = 0; i < 4; ++i) {
    const int d = db + ty + i * 8;
    Vt[(size_t)(bh * 64 + d) * 1024 + kvb + tx] = t[tx][ty + i * 8];
  }
}

// ---------- r8 GEMM: BARRIER-FREE, LDS-FREE. A = RBF(h) expanded in-register
// (basis region) or fragment-order Sf loads (silu region); B = fragment-order
// global (r6-proven). Pure load/MFMA stream, compiler pipelines with
// fine-grained vmcnt — the AITER K-loop shape. Grid is M-fast so concurrent
// blocks share one B panel per XCD (~3.5MB <= 4MB L2).
#define LOADB(dst, ktv)                                                   \
  { _Pragma("unroll") for (int ni = 0; ni < 2; ++ni)                      \
      _Pragma("unroll") for (int ks = 0; ks < 4; ++ks)                    \
        dst[ni][ks] = *(const h8*)(bpp[ni] + (size_t)(ktv) * 2048 + ks * 512); }

#define LOADH(dst, kgv)                                                   \
  { _Pragma("unroll") for (int mi = 0; mi < 2; ++mi)                      \
      _Pragma("unroll") for (int ks = 0; ks < 4; ++ks)                    \
        dst[mi][ks] = Ht[(size_t)((kgv) * 8 + ks * 2 + half) * 8192 + am0 + mi * 32]; }

#define STEP(bc, hc, kgv)                                                 \
  {                                                                       \
    if ((kgv) < 96) {                                                     \
      _Pragma("unroll") for (int ks = 0; ks < 4; ++ks) {                  \
        h8 a0 = rbf8((float)hc[0][ks]);                                   \
        h8 a1 = rbf8((float)hc[1][ks]);                                   \
        acc[0][0] = __builtin_amdgcn_mfma_f32_32x32x16_f16(a0, bc[0][ks], acc[0][0], 0, 0, 0); \
        acc[0][1] = __builtin_amdgcn_mfma_f32_32x32x16_f16(a0, bc[1][ks], acc[0][1], 0, 0, 0); \
        acc[1][0] = __builtin_amdgcn_mfma_f32_32x32x16_f16(a1, bc[0][ks], acc[1][0], 0, 0, 0); \
        acc[1][1] = __builtin_amdgcn_mfma_f32_32x32x16_f16(a1, bc[1][ks], acc[1][1], 0, 0, 0); \
      }                                                                   \
    } else {                                                              \
      const size_t tb = (size_t)((kgv) - 96) * 2048;                      \
      _Pragma("unroll") for (int ks = 0; ks < 4; ++ks) {                  \
        h8 a0 = *(const h8*)(Sf + sfB0 + tb + ks * 512);                  \
        h8 a1 = *(const h8*)(Sf + sfB1 + tb + ks * 512);                  \
        acc[0][0] = __builtin_amdgcn_mfma_f32_32x32x16_f16(a0, bc[0][ks], acc[0][0], 0, 0, 0); \
        acc[0][1] = __builtin_amdgcn_mfma_f32_32x32x16_f16(a0, bc[1][ks], acc[0][1], 0, 0, 0); \
        acc[1][0] = __builtin_amdgcn_mfma_f32_32x32x16_f16(a1, bc[0][ks], acc[1][0], 0, 0, 0); \
        acc[1][1] = __builtin_amdgcn_mfma_f32_32x32x16_f16(a1, bc[1][ks], acc[1][1], 0, 0, 0); \
      }                                                                   \
    }                                                                     \
  }

template <bool F16OUT>
__global__ __launch_bounds__(256, 2)
void gemm_fused(const _Float16* __restrict__ Ht, const _Float16* __restrict__ Sf,
                const _Float16* __restrict__ Bp, const float* __restrict__ bias,
                void* __restrict__ Cout, int N, int ktPerSlice, int nktTot,
                size_t sliceStride) {
  const int tid = threadIdx.x;
  const int lane = tid & 63, wave = tid >> 6;
  const int bm = blockIdx.x * 128, bn = blockIdx.y * 128;   // M-fast grid
  const int slice = blockIdx.z;
  const int kt0 = slice * ktPerSlice;
  const int l31 = lane & 31, half = lane >> 5;
  const int wm = (wave >> 1) * 64, wn = (wave & 1) * 64;
  const int am0 = bm + wm + l31;
  const size_t sfB0 = ((size_t)((bm + wm) >> 5) * 12) * 2048 + (size_t)(l31 + 32 * half) * 8;
  const size_t sfB1 = ((size_t)((bm + wm + 32) >> 5) * 12) * 2048 + (size_t)(l31 + 32 * half) * 8;
  const _Float16* bpp[2];
#pragma unroll
  for (int ni = 0; ni < 2; ++ni)
    bpp[ni] = Bp + ((size_t)(((bn + wn) >> 5) + ni) * nktTot + kt0) * 2048 + lane * 8;

  f16f acc[2][2] = {};
  h8 bA[2][4], bB[2][4];
  _Float16 hA[2][4], hB[2][4];
  LOADB(bA, 0);
  if (kt0 < 96) LOADH(hA, kt0);
  const int nkt = ktPerSlice;  // even (108 or 54)
  for (int kt = 0; kt < nkt; kt += 2) {
    const int kg0 = kt0 + kt, kg1 = kg0 + 1;
    LOADB(bB, kt + 1);
    if (kg1 < 96) LOADH(hB, kg1);
    STEP(bA, hA, kg0);
    if (kt + 2 < nkt) {
      LOADB(bA, kt + 2);
      if (kg0 + 2 < 96) LOADH(hA, kg0 + 2);
    }
    STEP(bB, hB, kg1);
  }
  // epilogue: 32x32 C/D layout col=lane&31, row=(reg&3)+8*(reg>>2)+4*(lane>>5)
#pragma unroll
  for (int ni = 0; ni < 2; ++ni) {
    const int col = bn + wn + ni * 32 + l31;
    const float bv = F16OUT ? bias[col] : 0.0f;
#pragma unroll
    for (int mi = 0; mi < 2; ++mi) {
      const int rb = bm + wm + mi * 32 + 4 * half;
#pragma unroll
      for (int reg = 0; reg < 16; ++reg) {
        const int r = rb + (reg & 3) + 8 * (reg >> 2);
        const float v = acc[mi][ni][reg] + bv;
        if (F16OUT)
          ((_Float16*)Cout)[(size_t)r * N + col] = (_Float16)v;
        else
          ((float*)Cout + slice * sliceStride)[(size_t)r * N + col] = v;
      }
    }
  }
}

// ---------- split-K reduce: out = P0 + P1 + bias  (fp32, [8192][768])
__global__ __launch_bounds__(256)
void ksum2(const float* __restrict__ P, const float* __restrict__ bias,
           float* __restrict__ out) {
  const size_t off = ((size_t)blockIdx.x * 256 + threadIdx.x) * 4;
  const int col = (int)(off % 768);
  f4 a = *(const f4*)(P + off);
  f4 b = *(const f4*)(P + (size_t)8192 * 768 + off);
  f4 c = *(const f4*)(bias + col);
  *(f4*)(out + off) = a + b + c;
}

// ---------- flash attention: grid (8 q-tiles, 96 bh). Q-tile 128, KV-tile 64.
__global__ __launch_bounds__(256)
void attn(const _Float16* __restrict__ qkv, const _Float16* __restrict__ Vt,
          float* __restrict__ ctx) {
  __shared__ __align__(16) _Float16 Qs[128 * 64];
  __shared__ __align__(16) _Float16 Ks[64 * 64];
  __shared__ __align__(16) _Float16 Vs[64 * 64];
  __shared__ __align__(16) _Float16 Ps[4 * 32 * 72];
  const int tid = threadIdx.x;
  const int lane = tid & 63, wave = tid >> 6;
  const int bh = blockIdx.y, hh = bh % 12, b = bh / 12;
  const int qt = blockIdx.x;
  const int rsub = lane >> 3;
  const int ksw = ((lane & 7) ^ rsub) * 8;
#pragma unroll
  for (int i = 0; i < 4; ++i) {
    const int ch = wave * 4 + i;
    const int row = ch * 8 + rsub;
    gld16(qkv + (size_t)(b * 1024 + qt * 128 + row) * 2304 + hh * 64 + ksw, Qs + ch * 512);
  }
  const int l16 = lane & 15, quad = lane >> 4, r7 = l16 & 7;
  f4 acc_o[2][4] = {};
  float m_old[2][4], l_sum[2][4];
#pragma unroll
  for (int mi = 0; mi < 2; ++mi)
#pragma unroll
    for (int j = 0; j < 4; ++j) { m_old[mi][j] = -1e30f; l_sum[mi][j] = 0.0f; }

  _Float16* Pw = Ps + wave * (32 * 72);

  for (int kv0 = 0; kv0 < 1024; kv0 += 64) {
#pragma unroll
    for (int i = 0; i < 2; ++i) {
      const int ch = wave * 2 + i;
      const int row = ch * 8 + rsub;
      gld16(qkv + (size_t)(b * 1024 + kv0 + row) * 2304 + 768 + hh * 64 + ksw, Ks + ch * 512);
      gld16(Vt + (size_t)(bh * 64 + row) * 1024 + kv0 + ksw, Vs + ch * 512);
    }
    __syncthreads();
    const h8* Q8 = (const h8*)Qs;
    const h8* K8 = (const h8*)Ks;
    const h8* V8 = (const h8*)Vs;
    f4 s[2][4] = {};
#pragma unroll
    for (int ks = 0; ks < 2; ++ks) {
      const int kq = (ks * 4 + quad) ^ r7;
      h8 qf[2], kf[4];
#pragma unroll
      for (int mi = 0; mi < 2; ++mi) qf[mi] = Q8[(wave * 32 + mi * 16 + l16) * 8 + kq];
#pragma unroll
      for (int ni = 0; ni < 4; ++ni) kf[ni] = K8[(ni * 16 + l16) * 8 + kq];
#pragma unroll
      for (int mi = 0; mi < 2; ++mi)
#pragma unroll
        for (int ni = 0; ni < 4; ++ni)
          s[mi][ni] = __builtin_amdgcn_mfma_f32_16x16x32_f16(qf[mi], kf[ni], s[mi][ni], 0, 0, 0);
    }
#pragma unroll
    for (int mi = 0; mi < 2; ++mi)
#pragma unroll
      for (int ni = 0; ni < 4; ++ni) s[mi][ni] *= 0.125f;  // d^-0.5, d=64
#pragma unroll
    for (int mi = 0; mi < 2; ++mi) {
#pragma unroll
      for (int j = 0; j < 4; ++j) {
        float vm = fmaxf(fmaxf(s[mi][0][j], s[mi][1][j]), fmaxf(s[mi][2][j], s[mi][3][j]));
#pragma unroll
        for (int off = 1; off < 16; off <<= 1) vm = fmaxf(vm, __shfl_xor(vm, off));
        const float mn = fmaxf(m_old[mi][j], vm);
        const float alpha = __expf(m_old[mi][j] - mn);
        float rs = 0.0f;
#pragma unroll
        for (int ni = 0; ni < 4; ++ni) {
          const float p = __expf(s[mi][ni][j] - mn);
          s[mi][ni][j] = p;
          rs += p;
        }
#pragma unroll
        for (int off = 1; off < 16; off <<= 1) rs += __shfl_xor(rs, off);
        l_sum[mi][j] = l_sum[mi][j] * alpha + rs;
        m_old[mi][j] = mn;
#pragma unroll
        for (int ni = 0; ni < 4; ++ni) acc_o[mi][ni][j] *= alpha;
      }
    }
#pragma unroll
    for (int mi = 0; mi < 2; ++mi)
#pragma unroll
      for (int ni = 0; ni < 4; ++ni)
#pragma unroll
        for (int j = 0; j < 4; ++j)
          Pw[(mi * 16 + quad * 4 + j) * 72 + ni * 16 + l16] = (_Float16)s[mi][ni][j];
#pragma unroll
    for (int ks = 0; ks < 2; ++ks) {
      const int kq = ks * 4 + quad;
      h8 pf[2], vf[4];
#pragma unroll
      for (int mi = 0; mi < 2; ++mi) pf[mi] = *(const h8*)(Pw + (mi * 16 + l16) * 72 + kq * 8);
#pragma unroll
      for (int ni = 0; ni < 4; ++ni) vf[ni] = V8[(ni * 16 + l16) * 8 + (kq ^ r7)];
#pragma unroll
      for (int mi = 0; mi < 2; ++mi)
#pragma unroll
        for (int ni = 0; ni < 4; ++ni)
          acc_o[mi][ni] = __builtin_amdgcn_mfma_f32_16x16x32_f16(pf[mi], vf[ni], acc_o[mi][ni], 0, 0, 0);
    }
    __syncthreads();
  }
#pragma unroll
  for (int mi = 0; mi < 2; ++mi) {
#pragma unroll
    for (int j = 0; j < 4; ++j) {
      const float inv = 1.0f / l_sum[mi][j];
      const int tok = b * 1024 + qt * 128 + wave * 32 + mi * 16 + quad * 4 + j;
      float* cr = ctx + (size_t)tok * 768 + hh * 64;
#pragma unroll
      for (int ni = 0; ni < 4; ++ni) cr[ni * 16 + l16] = acc_o[mi][ni][j] * inv;
    }
  }
}

extern "C" void kernel_launch(void* const* d_in, const int* in_sizes, int n_in,
                              void* d_out, int out_size, void* d_ws, size_t ws_size,
                              hipStream_t stream) {
  (void)in_sizes; (void)n_in; (void)out_size; (void)ws_size;
  const float* x    = (const float*)d_in[0];
  const float* qlnw = (const float*)d_in[1];
  const float* qlnb = (const float*)d_in[2];
  const float* qsw  = (const float*)d_in[3];
  const float* qbw  = (const float*)d_in[4];
  const float* qbb  = (const float*)d_in[5];
  const float* plnw = (const float*)d_in[6];
  const float* plnb = (const float*)d_in[7];
  const float* psw  = (const float*)d_in[8];
  const float* pbw  = (const float*)d_in[9];
  const float* pbb  = (const float*)d_in[10];
  float* out = (float*)d_out;

  // workspace (fp16 unless noted), ~143 MB
  _Float16* WtQ = (_Float16*)d_ws;                     // [2304][6912] frag-order
  _Float16* WtP = WtQ + (size_t)2304 * 6912;           // [768][6912] frag-order
  _Float16* Ht  = WtP + (size_t)768 * 6912;            // [768][8192] transposed h
  _Float16* Sf  = Ht + (size_t)768 * 8192;             // silu frag-order, 6.29M
  _Float16* QKV = Sf + (size_t)256 * 12 * 2048;        // [8192][2304]
  _Float16* Vt  = QKV + (size_t)8192 * 2304;           // [96*64][1024]
  float* CTX = (float*)(Vt + (size_t)96 * 64 * 1024);  // [8192][768] fp32
  float* Pp = (float*)QKV;  // split-K partials alias dead QKV+Vt (2*8192*768*4B)

  dim3 blk(256);
  // weights -> fp16 fragment-order (nkt=108)
  wt_cast<<<dim3(192, 72), blk, 0, stream>>>(qsw, WtQ, 2304, 0, 108);
  wt_cast<<<dim3(24, 72),  blk, 0, stream>>>(qbw, WtQ, 2304, 6144, 108);
  wt_cast<<<dim3(192, 24), blk, 0, stream>>>(psw, WtP, 768, 0, 108);
  wt_cast<<<dim3(24, 24),  blk, 0, stream>>>(pbw, WtP, 768, 6144, 108);
  // FastKAN 1 -> qkv (fused basis GEMM)
  kan_prep2<<<256, blk, 0, stream>>>(x, qlnw, qlnb, Ht, Sf);
  gemm_fused<true><<<dim3(64, 18, 1), blk, 0, stream>>>(
      Ht, Sf, WtQ, qbb, QKV, 2304, 108, 108, 0);
  // attention
  v_transpose<<<dim3(32, 2, 96), blk, 0, stream>>>(QKV, Vt);
  attn<<<dim3(8, 96), blk, 0, stream>>>(QKV, Vt, CTX);
  // FastKAN 2 -> out (fused, split-K=2 + reduce)
  kan_prep2<<<256, blk, 0, stream>>>(CTX, plnw, plnb, Ht, Sf);
  gemm_fused<false><<<dim3(64, 6, 2), blk, 0, stream>>>(
      Ht, Sf, WtP, nullptr, Pp, 768, 54, 108, (size_t)8192 * 768);
  ksum2<<<8192 * 768 / 4 / 256, blk, 0, stream>>>(Pp, pbb, out);
}